// Round 1
// baseline (290.086 us; speedup 1.0000x reference)
//
#include <hip/hip_runtime.h>
#include <math.h>

// DeepWalk forward: embedding gathers + per-pair dot products -> loss & MRR.
// Inputs (setup_inputs order):
//   d_in[0] inputs  int32 [B_IN]
//   d_in[1] src     int32 [B_PAIRS, 1]
//   d_in[2] pos     int32 [B_PAIRS, 1]
//   d_in[3] negs    int32 [B_PAIRS, NUM_NEGS]
//   d_in[4] target_table  f32 [V, 128]
//   d_in[5] context_table f32 [V, 128]
// Output (flat f32): embedding [B_IN*128], context_embedding [B_IN*128], loss, mrr

constexpr int DIM  = 128;
constexpr int NNEG = 8;

__device__ __forceinline__ float softplusf(float x) {
    // numerically stable: max(x,0) + log1p(exp(-|x|))
    return fmaxf(x, 0.0f) + log1pf(expf(-fabsf(x)));
}

// Kernel 1: gather output embeddings (32 lanes per row, float4 each = 512B/row)
// and zero the two scalar accumulators.
__global__ __launch_bounds__(256) void gather_rows(
    const int*   __restrict__ inputs,
    const float* __restrict__ tgt,
    const float* __restrict__ ctx,
    float*       __restrict__ out_emb,
    float*       __restrict__ out_ctx,
    float*       __restrict__ scalars,
    int n_rows)
{
    if (blockIdx.x == 0 && threadIdx.x == 0) {
        scalars[0] = 0.0f;   // loss
        scalars[1] = 0.0f;   // mrr
    }
    int tid = blockIdx.x * blockDim.x + threadIdx.x;
    if (tid < n_rows * 32) {
        int row  = tid >> 5;
        int lane = tid & 31;
        size_t idx = (size_t)inputs[row];
        const float4* s1 = (const float4*)(tgt + idx * DIM);
        const float4* s2 = (const float4*)(ctx + idx * DIM);
        ((float4*)(out_emb + (size_t)row * DIM))[lane] = s1[lane];
        ((float4*)(out_ctx + (size_t)row * DIM))[lane] = s2[lane];
    }
}

// Kernel 2: one wave (64 lanes) per pair; each lane holds float2 of the src
// embedding; 9 context rows are loaded coalesced and dot-reduced via shfl_xor.
__global__ __launch_bounds__(256) void pair_loss(
    const int*   __restrict__ src,
    const int*   __restrict__ pos,
    const int*   __restrict__ negs,
    const float* __restrict__ tgt,
    const float* __restrict__ ctx,
    float*       __restrict__ scalars,
    int n_pairs,
    float inv_n)
{
    __shared__ float red[2 * 4];   // 4 waves/block x {loss, mrr}
    const int wib   = threadIdx.x >> 6;       // wave in block (0..3)
    const int lane  = threadIdx.x & 63;
    const int gwave = blockIdx.x * 4 + wib;
    const int nwaves = gridDim.x * 4;

    float loss_acc = 0.0f;
    float mrr_acc  = 0.0f;

    for (int b = gwave; b < n_pairs; b += nwaves) {
        size_t s = (size_t)src[b];                       // wave-uniform
        float2 e = ((const float2*)(tgt + s * DIM))[lane];

        int ci[1 + NNEG];
        ci[0] = pos[b];
#pragma unroll
        for (int n = 0; n < NNEG; ++n) ci[1 + n] = negs[(size_t)b * NNEG + n];

        float dots[1 + NNEG];
#pragma unroll
        for (int c = 0; c < 1 + NNEG; ++c) {
            float2 cv = ((const float2*)(ctx + (size_t)ci[c] * DIM))[lane];
            float p = e.x * cv.x + e.y * cv.y;
#pragma unroll
            for (int off = 32; off > 0; off >>= 1)
                p += __shfl_xor(p, off);
            dots[c] = p;                                  // all lanes hold full dot
        }

        float lg = dots[0];
        float l  = softplusf(-lg);
        int rank = 1;
#pragma unroll
        for (int n = 1; n <= NNEG; ++n) {
            l += softplusf(dots[n]);
            rank += (dots[n] >= lg) ? 1 : 0;              // ties favor negatives
        }
        loss_acc += l;
        mrr_acc  += 1.0f / (float)rank;
    }

    // every lane of a wave has identical accumulators -> lane 0 publishes
    if (lane == 0) {
        red[wib * 2 + 0] = loss_acc;
        red[wib * 2 + 1] = mrr_acc;
    }
    __syncthreads();
    if (threadIdx.x == 0) {
        float L = 0.0f, M = 0.0f;
#pragma unroll
        for (int w = 0; w < 4; ++w) { L += red[2 * w]; M += red[2 * w + 1]; }
        atomicAdd(&scalars[0], L);
        atomicAdd(&scalars[1], M * inv_n);
    }
}

extern "C" void kernel_launch(void* const* d_in, const int* in_sizes, int n_in,
                              void* d_out, int out_size, void* d_ws, size_t ws_size,
                              hipStream_t stream) {
    const int*   inputs = (const int*)d_in[0];
    const int*   src    = (const int*)d_in[1];
    const int*   pos    = (const int*)d_in[2];
    const int*   negs   = (const int*)d_in[3];
    const float* tgt    = (const float*)d_in[4];
    const float* ctx    = (const float*)d_in[5];

    const int b_in    = in_sizes[0];
    const int b_pairs = in_sizes[1];

    float* out      = (float*)d_out;
    float* out_emb  = out;
    float* out_ctx  = out + (size_t)b_in * DIM;
    float* scalars  = out + (size_t)2 * b_in * DIM;   // [loss, mrr]

    // Kernel 1: 32 threads per row -> b_in*32 threads
    {
        int total  = b_in * 32;
        int blocks = (total + 255) / 256;
        gather_rows<<<blocks, 256, 0, stream>>>(inputs, tgt, ctx,
                                                out_emb, out_ctx, scalars, b_in);
    }
    // Kernel 2: one wave per pair, grid-stride; 2048 blocks = 8192 waves
    {
        int blocks = 2048;
        float inv_n = 1.0f / (float)b_pairs;
        pair_loss<<<blocks, 256, 0, stream>>>(src, pos, negs, tgt, ctx,
                                              scalars, b_pairs, inv_n);
    }
}

// Round 2
// 133.884 us; speedup vs baseline: 2.1667x; 2.1667x over previous
//
#include <hip/hip_runtime.h>
#include <math.h>

// DeepWalk forward: embedding gathers + per-pair dot products -> loss & MRR.
// Round 2: pair_loss restructured 16-lanes-per-pair (4 pairs/wave) to cut
// wave-instruction count ~4x (was VALU/issue-bound at 83% VALUBusy, 14% HBM).

constexpr int DIM  = 128;
constexpr int NNEG = 8;

// Kernel 1: gather output embeddings (32 lanes per row, float4 each = 512B/row)
// and zero the two scalar accumulators.
__global__ __launch_bounds__(256) void gather_rows(
    const int*   __restrict__ inputs,
    const float* __restrict__ tgt,
    const float* __restrict__ ctx,
    float*       __restrict__ out_emb,
    float*       __restrict__ out_ctx,
    float*       __restrict__ scalars,
    int n_rows)
{
    if (blockIdx.x == 0 && threadIdx.x == 0) {
        scalars[0] = 0.0f;   // loss
        scalars[1] = 0.0f;   // mrr
    }
    int tid = blockIdx.x * blockDim.x + threadIdx.x;
    if (tid < n_rows * 32) {
        int row  = tid >> 5;
        int lane = tid & 31;
        size_t idx = (size_t)inputs[row];
        const float4* s1 = (const float4*)(tgt + idx * DIM);
        const float4* s2 = (const float4*)(ctx + idx * DIM);
        ((float4*)(out_emb + (size_t)row * DIM))[lane] = s1[lane];
        ((float4*)(out_ctx + (size_t)row * DIM))[lane] = s2[lane];
    }
}

// Kernel 2: 16 lanes per pair (lane holds 8 floats = 2 x float4), 4 pairs per
// wave. Dot reduce = 4 shfl_xor stages within 16 lanes. Loss uses
// sum(softplus) = log(prod(1+exp)) to cut 9 logs -> 1.
__global__ __launch_bounds__(256) void pair_loss(
    const int*   __restrict__ src,
    const int*   __restrict__ pos,
    const int*   __restrict__ negs,
    const float* __restrict__ tgt,
    const float* __restrict__ ctx,
    float*       __restrict__ scalars,
    int n_pairs,
    float inv_n)
{
    __shared__ float red[2 * 4];   // 4 waves/block x {loss, mrr}
    const int lane = threadIdx.x & 63;
    const int l16  = threadIdx.x & 15;
    const int gid  = (blockIdx.x * blockDim.x + threadIdx.x) >> 4;
    const int ngroups = (gridDim.x * blockDim.x) >> 4;

    float loss_acc = 0.0f;
    float mrr_acc  = 0.0f;

    for (int b = gid; b < n_pairs; b += ngroups) {
        // src row: 8 floats per lane, 16 lanes = full 512B row
        int sidx = src[b];                                   // group-uniform
        const float4* srow = (const float4*)(tgt + (size_t)sidx * DIM);
        float4 e0 = srow[l16 * 2 + 0];
        float4 e1 = srow[l16 * 2 + 1];

        // context indices: pos + 8 negs (negs vectorized as 2 x int4)
        int ci[1 + NNEG];
        ci[0] = pos[b];
        const int4* np = (const int4*)(negs + (size_t)b * NNEG);
        int4 n0 = np[0];
        int4 n1 = np[1];
        ci[1] = n0.x; ci[2] = n0.y; ci[3] = n0.z; ci[4] = n0.w;
        ci[5] = n1.x; ci[6] = n1.y; ci[7] = n1.z; ci[8] = n1.w;

        float dots[1 + NNEG];
#pragma unroll
        for (int c = 0; c < 1 + NNEG; ++c) {
            const float4* crow = (const float4*)(ctx + (size_t)ci[c] * DIM);
            float4 c0 = crow[l16 * 2 + 0];
            float4 c1 = crow[l16 * 2 + 1];
            float pa = e0.x * c0.x + e0.y * c0.y + e0.z * c0.z + e0.w * c0.w;
            float pb = e1.x * c1.x + e1.y * c1.y + e1.z * c1.z + e1.w * c1.w;
            float p  = pa + pb;
#pragma unroll
            for (int off = 8; off > 0; off >>= 1)
                p += __shfl_xor(p, off, 16);
            dots[c] = p;                    // all 16 lanes of the group hold it
        }

        // loss: softplus(-lg) + sum_n softplus(dn) = log((1+e^-lg)*prod(1+e^dn))
        float lg   = dots[0];
        float prod = 1.0f + __expf(-lg);
        int rank = 1;
#pragma unroll
        for (int n = 1; n <= NNEG; ++n) {
            prod *= 1.0f + __expf(dots[n]);
            rank += (dots[n] >= lg) ? 1 : 0;   // ties favor negatives
        }
        loss_acc += __logf(prod);
        mrr_acc  += 1.0f / (float)rank;
    }

    // group lanes hold identical acc -> keep only l16==0, reduce across wave
    float L = (l16 == 0) ? loss_acc : 0.0f;
    float M = (l16 == 0) ? mrr_acc  : 0.0f;
#pragma unroll
    for (int off = 32; off > 0; off >>= 1) {
        L += __shfl_xor(L, off);
        M += __shfl_xor(M, off);
    }
    const int wib = threadIdx.x >> 6;
    if (lane == 0) {
        red[wib * 2 + 0] = L;
        red[wib * 2 + 1] = M;
    }
    __syncthreads();
    if (threadIdx.x == 0) {
        float Ls = 0.0f, Ms = 0.0f;
#pragma unroll
        for (int w = 0; w < 4; ++w) { Ls += red[2 * w]; Ms += red[2 * w + 1]; }
        atomicAdd(&scalars[0], Ls);
        atomicAdd(&scalars[1], Ms * inv_n);
    }
}

extern "C" void kernel_launch(void* const* d_in, const int* in_sizes, int n_in,
                              void* d_out, int out_size, void* d_ws, size_t ws_size,
                              hipStream_t stream) {
    const int*   inputs = (const int*)d_in[0];
    const int*   src    = (const int*)d_in[1];
    const int*   pos    = (const int*)d_in[2];
    const int*   negs   = (const int*)d_in[3];
    const float* tgt    = (const float*)d_in[4];
    const float* ctx    = (const float*)d_in[5];

    const int b_in    = in_sizes[0];
    const int b_pairs = in_sizes[1];

    float* out      = (float*)d_out;
    float* out_emb  = out;
    float* out_ctx  = out + (size_t)b_in * DIM;
    float* scalars  = out + (size_t)2 * b_in * DIM;   // [loss, mrr]

    // Kernel 1: 32 threads per row -> b_in*32 threads
    {
        int total  = b_in * 32;
        int blocks = (total + 255) / 256;
        gather_rows<<<blocks, 256, 0, stream>>>(inputs, tgt, ctx,
                                                out_emb, out_ctx, scalars, b_in);
    }
    // Kernel 2: 16 lanes/pair, 4 pairs/wave; 2048 blocks -> 32768 groups
    {
        int blocks = 2048;
        float inv_n = 1.0f / (float)b_pairs;
        pair_loss<<<blocks, 256, 0, stream>>>(src, pos, negs, tgt, ctx,
                                              scalars, b_pairs, inv_n);
    }
}

// Round 4
// 126.176 us; speedup vs baseline: 2.2991x; 1.0611x over previous
//
#include <hip/hip_runtime.h>
#include <math.h>

// DeepWalk forward: embedding gathers + per-pair dot products -> loss & MRR.
// Round 4: round-3 design with the nontemporal builtin fixed (needs a native
// clang ext_vector_type, not HIP_vector_type). Single fused kernel (gather
// phase + pair phase), per-block partials in d_ws + tiny finalize kernel,
// non-temporal copies in the gather phase to keep L2/LLC for table rows.

constexpr int DIM  = 128;
constexpr int NNEG = 8;

typedef float f32x4 __attribute__((ext_vector_type(4)));

__global__ __launch_bounds__(256) void fused(
    const int*   __restrict__ inputs,
    const int*   __restrict__ src,
    const int*   __restrict__ pos,
    const int*   __restrict__ negs,
    const float* __restrict__ tgt,
    const float* __restrict__ ctx,
    float*       __restrict__ out_emb,
    float*       __restrict__ out_ctx,
    float*       __restrict__ partials,   // [gridDim.x * 2]
    int b_in,
    int n_pairs)
{
    const int tid     = blockIdx.x * blockDim.x + threadIdx.x;
    const int nthread = gridDim.x * blockDim.x;

    // ---------------- phase 1: output gathers (copy, no reuse) -------------
    // unit u -> (row, table, lane): one wave handles one input row for BOTH
    // tables (lanes 0-31 tgt, lanes 32-63 ctx); index load is wave-uniform.
    {
        const int total = b_in * 64;
        for (int u = tid; u < total; u += nthread) {
            int row   = u >> 6;
            int sub   = u & 63;
            int table = sub >> 5;
            int lane  = sub & 31;
            size_t idx = (size_t)inputs[row];
            const f32x4* s = (const f32x4*)((table ? ctx : tgt) + idx * DIM);
            f32x4 v = __builtin_nontemporal_load(s + lane);
            f32x4* d = (f32x4*)((table ? out_ctx : out_emb) + (size_t)row * DIM);
            __builtin_nontemporal_store(v, d + lane);
        }
    }

    // ---------------- phase 2: pair loss / mrr -----------------------------
    // 16 lanes per pair (lane holds 8 floats = 2 x float4), 4 pairs per wave.
    const int lane = threadIdx.x & 63;
    const int l16  = threadIdx.x & 15;
    const int gid  = tid >> 4;
    const int ngroups = nthread >> 4;

    float loss_acc = 0.0f;
    float mrr_acc  = 0.0f;

    for (int b = gid; b < n_pairs; b += ngroups) {
        int sidx = src[b];                                   // group-uniform
        const float4* srow = (const float4*)(tgt + (size_t)sidx * DIM);
        float4 e0 = srow[l16 * 2 + 0];
        float4 e1 = srow[l16 * 2 + 1];

        int ci[1 + NNEG];
        ci[0] = pos[b];
        const int4* np = (const int4*)(negs + (size_t)b * NNEG);
        int4 n0 = np[0];
        int4 n1 = np[1];
        ci[1] = n0.x; ci[2] = n0.y; ci[3] = n0.z; ci[4] = n0.w;
        ci[5] = n1.x; ci[6] = n1.y; ci[7] = n1.z; ci[8] = n1.w;

        float dots[1 + NNEG];
#pragma unroll
        for (int c = 0; c < 1 + NNEG; ++c) {
            const float4* crow = (const float4*)(ctx + (size_t)ci[c] * DIM);
            float4 c0 = crow[l16 * 2 + 0];
            float4 c1 = crow[l16 * 2 + 1];
            float pa = e0.x * c0.x + e0.y * c0.y + e0.z * c0.z + e0.w * c0.w;
            float pb = e1.x * c1.x + e1.y * c1.y + e1.z * c1.z + e1.w * c1.w;
            float p  = pa + pb;
#pragma unroll
            for (int off = 8; off > 0; off >>= 1)
                p += __shfl_xor(p, off, 16);
            dots[c] = p;                    // all 16 lanes of the group hold it
        }

        // sum softplus(-lg) + sum_n softplus(dn) = log((1+e^-lg)*prod(1+e^dn))
        // |dot| <= ~4 (rows ~unit norm) -> no overflow concern in the product.
        float lg   = dots[0];
        float prod = 1.0f + __expf(-lg);
        int rank = 1;
#pragma unroll
        for (int n = 1; n <= NNEG; ++n) {
            prod *= 1.0f + __expf(dots[n]);
            rank += (dots[n] >= lg) ? 1 : 0;   // ties favor negatives
        }
        loss_acc += __logf(prod);
        mrr_acc  += 1.0f / (float)rank;
    }

    // group lanes hold identical acc -> keep l16==0 lanes, butterfly the wave
    float L = (l16 == 0) ? loss_acc : 0.0f;
    float M = (l16 == 0) ? mrr_acc  : 0.0f;
#pragma unroll
    for (int off = 32; off > 0; off >>= 1) {
        L += __shfl_xor(L, off);
        M += __shfl_xor(M, off);
    }
    __shared__ float red[2 * 4];
    const int wib = threadIdx.x >> 6;
    if (lane == 0) {
        red[wib * 2 + 0] = L;
        red[wib * 2 + 1] = M;
    }
    __syncthreads();
    if (threadIdx.x == 0) {
        float Ls = 0.0f, Ms = 0.0f;
#pragma unroll
        for (int w = 0; w < 4; ++w) { Ls += red[2 * w]; Ms += red[2 * w + 1]; }
        partials[blockIdx.x * 2 + 0] = Ls;
        partials[blockIdx.x * 2 + 1] = Ms;
    }
}

// 1-block reduction of per-block partials -> scalars {loss, mrr}
__global__ __launch_bounds__(256) void finalize(
    const float* __restrict__ partials,
    float*       __restrict__ scalars,
    int nblocks,
    float inv_n)
{
    float L = 0.0f, M = 0.0f;
    for (int i = threadIdx.x; i < nblocks; i += 256) {
        L += partials[2 * i + 0];
        M += partials[2 * i + 1];
    }
#pragma unroll
    for (int off = 32; off > 0; off >>= 1) {
        L += __shfl_xor(L, off);
        M += __shfl_xor(M, off);
    }
    __shared__ float red[2 * 4];
    const int wib = threadIdx.x >> 6;
    if ((threadIdx.x & 63) == 0) {
        red[wib * 2 + 0] = L;
        red[wib * 2 + 1] = M;
    }
    __syncthreads();
    if (threadIdx.x == 0) {
        float Ls = 0.0f, Ms = 0.0f;
#pragma unroll
        for (int w = 0; w < 4; ++w) { Ls += red[2 * w]; Ms += red[2 * w + 1]; }
        scalars[0] = Ls;
        scalars[1] = Ms * inv_n;
    }
}

extern "C" void kernel_launch(void* const* d_in, const int* in_sizes, int n_in,
                              void* d_out, int out_size, void* d_ws, size_t ws_size,
                              hipStream_t stream) {
    const int*   inputs = (const int*)d_in[0];
    const int*   src    = (const int*)d_in[1];
    const int*   pos    = (const int*)d_in[2];
    const int*   negs   = (const int*)d_in[3];
    const float* tgt    = (const float*)d_in[4];
    const float* ctx    = (const float*)d_in[5];

    const int b_in    = in_sizes[0];
    const int b_pairs = in_sizes[1];

    float* out      = (float*)d_out;
    float* out_emb  = out;
    float* out_ctx  = out + (size_t)b_in * DIM;
    float* scalars  = out + (size_t)2 * b_in * DIM;   // [loss, mrr]
    float* partials = (float*)d_ws;                    // [blocks * 2]

    // 2048 blocks x 256 = 8192 waves = exactly 32 waves/CU on 256 CUs.
    const int blocks = 2048;
    fused<<<blocks, 256, 0, stream>>>(inputs, src, pos, negs, tgt, ctx,
                                      out_emb, out_ctx, partials,
                                      b_in, b_pairs);
    finalize<<<1, 256, 0, stream>>>(partials, scalars, blocks,
                                    1.0f / (float)b_pairs);
}